// Round 15
// baseline (848.031 us; speedup 1.0000x reference)
//
#include <hip/hip_runtime.h>
#include <hip/hip_fp16.h>

#define BB 2
#define HH 512
#define WW 512
#define CC 64
#define PW 514
#define ROWS 8

typedef _Float16 f16;
typedef _Float16 f16x8 __attribute__((ext_vector_type(8)));
typedef float f32x4 __attribute__((ext_vector_type(4)));

static __device__ __forceinline__ f16x8 zero_f16x8() {
    f16x8 z = {(f16)0,(f16)0,(f16)0,(f16)0,(f16)0,(f16)0,(f16)0,(f16)0};
    return z;
}

static __device__ __forceinline__ f16x8 cvt_pair(f32x4 a, f32x4 b) {
    f16x8 o;
    o[0]=(f16)a[0]; o[1]=(f16)a[1]; o[2]=(f16)a[2]; o[3]=(f16)a[3];
    o[4]=(f16)b[0]; o[5]=(f16)b[1]; o[6]=(f16)b[2]; o[7]=(f16)b[3];
    return o;
}

// ---------------------------------------------------------------- prep: ch
__global__ void k_prep_ch(const float* __restrict__ gum, const float* __restrict__ chm,
                          float* __restrict__ ws_ch, float* __restrict__ out_ch) {
    int t = threadIdx.x;           // 256 threads, one (l,c) pair each
    int l = t >> 6, c = t & 63;
    float u0 = gum[(l*2+0)*64+c], u1 = gum[(l*2+1)*64+c];
    u0 = fminf(fmaxf(u0, 1e-10f), 1.0f);
    u1 = fminf(fmaxf(u1, 1e-10f), 1.0f);
    float a0 = chm[(l*2+0)*64+c] - logf(-logf(u0));   // TAU = 1
    float a1 = chm[(l*2+1)*64+c] - logf(-logf(u1));
    float m = fmaxf(a0, a1);
    float e0 = expf(a0-m), e1 = expf(a1-m);
    float s = e0 + e1;
    float c0 = e0/s, c1 = e1/s;
    ws_ch[(l*2+0)*64+c] = c0;  ws_ch[(l*2+1)*64+c] = c1;
    out_ch[(l*2+0)*64+c] = c0; out_ch[(l*2+1)*64+c] = c1;
}

// ------------------------------------------------------------ weight packing
// Bpk layout: [kb][nbTot][lane][8] f16, fragment-direct for mfma 16x16x32.
__global__ void k_pack(const float* __restrict__ w0, const float* __restrict__ w1,
                       const float* __restrict__ w2, const float* __restrict__ w3,
                       const float* __restrict__ wc, const float* __restrict__ ch,
                       f16* __restrict__ bpk0, f16* __restrict__ bpkL, f16* __restrict__ wcpk) {
    int idx = blockIdx.x * 256 + threadIdx.x;
    if (idx < 36864) {
        int j = idx & 7, lane = (idx>>3)&63, nb = (idx>>9)&3, kb = idx>>11;
        int k = kb*32 + (lane>>4)*8 + j;
        int tap = k>>6, ci = k&63;
        int co = nb*16 + (lane&15);
        bpk0[idx] = (f16)w0[(tap*64+ci)*64+co];
    } else if (idx < 36864 + 221184) {
        int i2 = idx - 36864;
        int l = i2 / 73728;               // 0..2 -> layer l+1, masks from ch[l]
        int r = i2 % 73728;
        int j = r&7, lane=(r>>3)&63, nb=(r>>9)&7, kb=r>>12;
        int k = kb*32 + (lane>>4)*8 + j;
        int tap = k>>6, ci = k&63;
        int copr = nb*16 + (lane&15);     // 0..127, [0:64)=dense, [64:128)=sparse
        int co = copr & 63;
        const float* w = (l==0)? w1 : (l==1)? w2 : w3;
        float scale = (copr < 64) ? ch[(l*2+0)*64+ci] : ch[(l*2+1)*64+ci];
        bpkL[i2] = (f16)(w[(tap*64+ci)*64+co] * scale);
    } else if (idx < 36864 + 221184 + 16384) {
        int i3 = idx - (36864 + 221184);
        int j=i3&7, lane=(i3>>3)&63, nb=(i3>>9)&3, kb=(i3>>11)&1, l=i3>>12;
        int k = kb*32 + (lane>>4)*8 + j;
        int n = nb*16 + (lane&15);
        wcpk[i3] = (f16)wc[(l*64+k)*64+n];
    }
}

// ---------------------------------------------- zero the guard ring of a fea
__global__ void k_guard(f16* __restrict__ buf) {
    int idx = blockIdx.x*256 + threadIdx.x;       // 16B units
    const int TOT = 2*2052*8;
    if (idx >= TOT) return;
    int c8 = idx & 7, g = idx >> 3;
    int b = g / 2052, r = g % 2052;
    int hp, wp;
    if      (r < 514)  { hp = 0;        wp = r; }
    else if (r < 1028) { hp = 513;      wp = r-514; }
    else if (r < 1540) { hp = r-1027;   wp = 0; }
    else               { hp = r-1539;   wp = 513; }
    *(f16x8*)(buf + ((size_t)(b*PW+hp)*PW + wp)*64 + c8*8) = zero_f16x8();
}

// ------------------------------------------------------------------- conv
// ROW-STREAMING: block = 4 waves (2M x 2N), 128-px strip, ROWS=8 output
// rows. LDS = 4-row ring (slot = padded_row & 3, 69632 B -> 2 blocks/CU).
// Per step i (output row h0+i): barrier -> issue stage of padded row
// h0+i+3 into slot (i+3)&3 (disjoint from the 3 read slots) -> compute
// 18 kb on slots (i..i+2)&3 -> epilogue -> (MODE0: cvt+ds_write payload).
// Stage latency hides under the 18-kb MFMA phase; the barrier's vmcnt(0)
// drain hits loads issued a full compute phase earlier.
// Wave tile: 64 px x 32 co (x {D,S} for MODE1): acc[4][NF].
// B register-double-buffered within each row. MFMAs under setprio(1).
// LDS sub-slots XOR-swizzled (rule 21): cblk = sub ^ srel.
// MODE 0: raw f32 x0 input, cvt fused (payload regs, pinned issue).
//         N=64, out = relu(conv * (cs*spa + cd)).
// MODE 1: padded f16 input, global_load_lds staging.
//         N=128, out = relu(D*(cs*spa+cd) + S*spa).
template<int MODE>
__global__ __launch_bounds__(256, 2) void k_conv(const void* __restrict__ in_, f16* __restrict__ out,
        const f16* __restrict__ bpk, const float* __restrict__ ch_l,
        const float* __restrict__ spa) {
    constexpr int NBT = (MODE==0) ? 4 : 8;
    constexpr int NF  = (MODE==0) ? 2 : 4;
    __shared__ f16 smem[4*136*64];                 // 69632 B ring
    char* smb = (char*)smem;
    const int wt = blockIdx.x, by = blockIdx.y, b = blockIdx.z;
    const int h0 = by*ROWS;                        // h0 % 8 == 0 -> h0 & 3 == 0
    const int tid = threadIdx.x, lane = tid & 63, wid = tid >> 6;
    const int px0 = wt*128;
    const int sub  = lane & 7;
    const int srel = lane >> 3;
    const int cblk = sub ^ srel;                   // s&7 == srel for s=i2*8+srel

    const float* inF = (const float*)in_;
    const f16*   inH = (const f16*)in_;

    // MODE0 stage payload (one row, written at end of step)
    f32x4 pv0[5], pv1[5];
    bool pok[5];
    int pdst[5];

    // ---- prologue: stage padded rows h0, h0+1, h0+2 (slots 0,1,2) ----
    if (MODE == 0) {
        #pragma unroll
        for (int r = 0; r < 3; ++r) {
            const int p = h0 + r;
            const int hin = p - 1;
            #pragma unroll
            for (int t = 0; t < 5; ++t) {
                int i2 = t*4 + wid;
                pok[t] = false;
                if (i2 < 17) {
                    int s = i2*8 + srel;
                    int win = px0 + s - 1;
                    pok[t] = ((unsigned)hin < HH) && ((unsigned)win < WW);
                    pdst[t] = (p&3)*17408 + i2*1024 + lane*16;
                    if (pok[t]) {
                        const f32x4* pp = (const f32x4*)(inF + (((size_t)(b*HH + hin)*WW + win)*CC + cblk*8));
                        pv0[t] = pp[0];
                        pv1[t] = pp[1];
                    }
                }
            }
            #pragma unroll
            for (int t = 0; t < 5; ++t) {
                if (t*4 + wid < 17) {
                    f16x8 o = pok[t] ? cvt_pair(pv0[t], pv1[t]) : zero_f16x8();
                    *(f16x8*)(smb + pdst[t]) = o;
                }
            }
        }
    } else {
        #pragma unroll
        for (int r = 0; r < 3; ++r) {
            const int p = h0 + r;
            #pragma unroll
            for (int t = 0; t < 5; ++t) {
                int i2 = t*4 + wid;
                if (i2 < 17) {
                    int s = i2*8 + srel;
                    const f16* src = inH + ((size_t)(b*PW + p)*PW + (px0 + s))*64 + cblk*8;
                    __builtin_amdgcn_global_load_lds(
                        (const __attribute__((address_space(1))) uint32_t*)src,
                        (__attribute__((address_space(3))) uint32_t*)
                            (smb + (p&3)*17408 + i2*1024),
                        16, 0, 0);
                }
            }
        }
    }

    const int wm = wid >> 1, wn = wid & 1;
    const int lrow = lane & 15, q = lane >> 4;

    // per-lane LDS read offsets: in-row slot s = wm*64+mf*16+lrow+dxi
    int sb[4][3], po[2][3];
    #pragma unroll
    for (int dxi = 0; dxi < 3; ++dxi) {
        int m7 = (lrow + dxi) & 7;
        po[0][dxi] = ((q)     ^ m7) * 16;
        po[1][dxi] = ((4 + q) ^ m7) * 16;
        #pragma unroll
        for (int mf = 0; mf < 4; ++mf)
            sb[mf][dxi] = (wm*64 + mf*16 + lrow + dxi) * 128;
    }

    int nbIdx[4];
    nbIdx[0]=wn*2; nbIdx[1]=wn*2+1; nbIdx[2]=wn*2+4; nbIdx[3]=wn*2+5;
    const f16* blane = bpk + (size_t)lane*8;       // + kb*NBT*512 + nb*512

    const float* cd = ch_l;
    const float* cs = ch_l + 64;

    for (int i = 0; i < ROWS; ++i) {
        __syncthreads();                           // staged row (i+2) visible; ring safe

        // ---- issue stage of padded row h0+i+3 -> slot (i+3)&3 ----
        if (i < ROWS-1) {
            const int p = h0 + i + 3;
            if (MODE == 0) {
                const int hin = p - 1;             // h0+i+2 >= 2
                #pragma unroll
                for (int t = 0; t < 5; ++t) {
                    int i2 = t*4 + wid;
                    pok[t] = false;
                    if (i2 < 17) {
                        int s = i2*8 + srel;
                        int win = px0 + s - 1;
                        pok[t] = (hin < HH) && ((unsigned)win < WW);
                        pdst[t] = (p&3)*17408 + i2*1024 + lane*16;
                        if (pok[t]) {
                            const f32x4* pp = (const f32x4*)(inF + (((size_t)(b*HH + hin)*WW + win)*CC + cblk*8));
                            pv0[t] = pp[0];
                            pv1[t] = pp[1];
                        }
                    }
                }
                __builtin_amdgcn_sched_barrier(0); // pin load issue before compute
            } else {
                #pragma unroll
                for (int t = 0; t < 5; ++t) {
                    int i2 = t*4 + wid;
                    if (i2 < 17) {
                        int s = i2*8 + srel;
                        const f16* src = inH + ((size_t)(b*PW + p)*PW + (px0 + s))*64 + cblk*8;
                        __builtin_amdgcn_global_load_lds(
                            (const __attribute__((address_space(1))) uint32_t*)src,
                            (__attribute__((address_space(3))) uint32_t*)
                                (smb + (p&3)*17408 + i2*1024),
                            16, 0, 0);
                    }
                }
            }
        }

        // ---- compute output row h0+i: 18 k-blocks ----
        f32x4 acc[4][NF];
        #pragma unroll
        for (int m=0;m<4;m++)
            #pragma unroll
            for (int j=0;j<NF;j++) { f32x4 z = {0.f,0.f,0.f,0.f}; acc[m][j] = z; }

        f16x8 acur[4], bcur[NF], bnxt[NF];
        #pragma unroll
        for (int nf=0; nf<NF; ++nf)
            bcur[nf] = *reinterpret_cast<const f16x8*>(blane + (size_t)nbIdx[nf]*512);

        #pragma unroll
        for (int kb = 0; kb < 18; ++kb) {
            const int rn = kb/6, dxi = (kb%6)/2, half = kb & 1;
            const int slot = (i + rn) & 3;
            #pragma unroll
            for (int mf=0; mf<4; ++mf)
                acur[mf] = *(const f16x8*)(smb + slot*17408 + sb[mf][dxi] + po[half][dxi]);
            if (kb < 17) {
                const int kn = kb + 1;
                #pragma unroll
                for (int nf=0; nf<NF; ++nf)
                    bnxt[nf] = *reinterpret_cast<const f16x8*>(blane + (size_t)(kn*NBT + nbIdx[nf])*512);
            }
            __builtin_amdgcn_s_setprio(1);
            #pragma unroll
            for (int nf=0; nf<NF; ++nf) {
                #pragma unroll
                for (int mf=0; mf<4; ++mf)
                    acc[mf][nf] = __builtin_amdgcn_mfma_f32_16x16x32_f16(acur[mf], bcur[nf], acc[mf][nf], 0,0,0);
            }
            __builtin_amdgcn_s_setprio(0);
            #pragma unroll
            for (int nf=0; nf<NF; ++nf) bcur[nf] = bnxt[nf];
        }

        // ---- epilogue row h0+i ----
        {
            const int h = h0 + i;
            const size_t sparow = (size_t)(b*HH + h)*WW;
            const size_t outrow = (size_t)(b*PW + h + 1)*PW + 1;
            #pragma unroll
            for (int mf=0; mf<4; ++mf) {
                const int pixb = wm*64 + mf*16 + q*4;
                f32x4 sp4 = *(const f32x4*)(spa + sparow + px0 + pixb);
                #pragma unroll
                for (int nf2=0; nf2<2; ++nf2) {
                    int co = wn*32 + nf2*16 + lrow;
                    float vcd = cd[co], vcs = cs[co];
                    #pragma unroll
                    for (int r=0; r<4; ++r) {
                        float sp = sp4[r];
                        float v;
                        if (MODE==0) v = acc[mf][nf2][r] * (vcs*sp + vcd);
                        else         v = acc[mf][nf2][r] * (vcs*sp + vcd) + acc[mf][nf2+2][r] * sp;
                        v = fmaxf(v, 0.f);
                        out[(outrow + px0 + pixb + r)*64 + co] = (f16)v;
                    }
                }
            }
        }

        // ---- MODE0: cvt + ds_write the payload (loads landed under compute) ----
        if (MODE == 0 && i < ROWS-1) {
            #pragma unroll
            for (int t = 0; t < 5; ++t) {
                if (t*4 + wid < 17) {
                    f16x8 o = pok[t] ? cvt_pair(pv0[t], pv1[t]) : zero_f16x8();
                    *(f16x8*)(smb + pdst[t]) = o;
                }
            }
        }
    }
}

// --------------------------------------------------- collect (single pass)
// out[p,co] = sum_l fea_l[p,:] @ Wc_l + bias.  K = 256. Padded f16 inputs.
// mfma(W, X, C) -> transposed C -> f32x4 (16B) plain stores. A-fragments
// register-double-buffered.
__global__ __launch_bounds__(256) void k_collect_all(
        const f16* __restrict__ f0, const f16* __restrict__ f1,
        const f16* __restrict__ f2, const f16* __restrict__ f3,
        const f16* __restrict__ wcpk, const float* __restrict__ bias,
        float* __restrict__ out) {
    const int wt = blockIdx.x, h = blockIdx.y, b = blockIdx.z;
    const int tid = threadIdx.x;
    const int lane = tid & 63, wid = tid >> 6;
    const int lrow = lane & 15, lk = (lane>>4)*8;
    const size_t inrow  = (size_t)(b*PW + h + 1)*PW + 1;
    const size_t outrow = (size_t)(b*HH + h)*WW;
    const int px0 = wt*256 + wid*64;

    const f16* feas[4] = {f0, f1, f2, f3};

    f32x4 acc[4][4];
    #pragma unroll
    for (int i=0;i<4;i++)
        #pragma unroll
        for (int j=0;j<4;j++) { f32x4 z = {0.f,0.f,0.f,0.f}; acc[i][j] = z; }

    f16x8 a_cur[4], a_nxt[4];
    #pragma unroll
    for (int mf=0; mf<4; ++mf)
        a_cur[mf] = *reinterpret_cast<const f16x8*>(f0 + (inrow + px0 + mf*16 + lrow)*64 + lk);

    #pragma unroll
    for (int kb=0; kb<8; ++kb) {
        if (kb < 7) {
            const f16* fl = feas[(kb+1)>>1];
            #pragma unroll
            for (int mf=0; mf<4; ++mf)
                a_nxt[mf] = *reinterpret_cast<const f16x8*>(fl + (inrow + px0 + mf*16 + lrow)*64 + ((kb+1)&1)*32 + lk);
        }
        #pragma unroll
        for (int nf=0; nf<4; ++nf) {
            f16x8 bb = *reinterpret_cast<const f16x8*>(wcpk + ((size_t)(kb*4 + nf)*64 + lane)*8);
            #pragma unroll
            for (int mf=0; mf<4; ++mf)
                acc[mf][nf] = __builtin_amdgcn_mfma_f32_16x16x32_f16(bb, a_cur[mf], acc[mf][nf], 0,0,0);
        }
        #pragma unroll
        for (int mf=0; mf<4; ++mf) a_cur[mf] = a_nxt[mf];
    }
    const int q = lane >> 4;
    #pragma unroll
    for (int mf=0; mf<4; ++mf) {
        const int pix = px0 + mf*16 + lrow;
        float* orow = out + (outrow + pix)*CC;
        #pragma unroll
        for (int nf=0; nf<4; ++nf) {
            const int co0 = nf*16 + q*4;
            f32x4 b4 = *(const f32x4*)(bias + co0);
            *(f32x4*)(orow + co0) = acc[mf][nf] + b4;
        }
    }
}

// --------------------------------------- collect fallback (per-layer RMW)
template<bool FIRST>
__global__ __launch_bounds__(256) void k_collect(const f16* __restrict__ fea,
        const f16* __restrict__ wcpk_l, const float* __restrict__ bias,
        float* __restrict__ out) {
    const int wt = blockIdx.x, h = blockIdx.y, b = blockIdx.z;
    const int tid = threadIdx.x;
    const int lane = tid & 63, wid = tid >> 6;
    const int lrow = lane & 15, lk = (lane>>4)*8;
    const size_t inrow  = (size_t)(b*PW + h + 1)*PW + 1;
    const size_t outrow = (size_t)(b*HH + h)*WW;
    const int px0 = wt*64 + wid*16;

    f32x4 acc[4];
    #pragma unroll
    for (int j=0;j<4;j++) { f32x4 z = {0.f,0.f,0.f,0.f}; acc[j] = z; }

    #pragma unroll
    for (int kb=0; kb<2; ++kb) {
        f16x8 a = *reinterpret_cast<const f16x8*>(fea + (inrow + px0 + lrow)*64 + kb*32 + lk);
        #pragma unroll
        for (int nf=0; nf<4; ++nf) {
            f16x8 bb = *reinterpret_cast<const f16x8*>(wcpk_l + ((size_t)(kb*4 + nf)*64 + lane)*8);
            acc[nf] = __builtin_amdgcn_mfma_f32_16x16x32_f16(bb, a, acc[nf], 0,0,0);
        }
    }
    const int q = lane >> 4;
    const int pix = px0 + lrow;
    float* orow = out + (outrow + pix)*CC;
    #pragma unroll
    for (int nf=0; nf<4; ++nf) {
        const int co0 = nf*16 + q*4;
        f32x4 v = acc[nf];
        #pragma unroll
        for (int r=0;r<4;++r) {
            float x = v[r];
            if (FIRST) x += bias[co0+r];
            else       x += orow[co0+r];
            orow[co0+r] = x;
        }
    }
}

// ------------------------------------------------------------------ launch
extern "C" void kernel_launch(void* const* d_in, const int* in_sizes, int n_in,
                              void* d_out, int out_size, void* d_ws, size_t ws_size,
                              hipStream_t stream) {
    const float* x0  = (const float*)d_in[0];
    const float* spa = (const float*)d_in[1];
    const float* gum = (const float*)d_in[2];
    const float* chm = (const float*)d_in[3];
    const float* w0  = (const float*)d_in[4];
    const float* w1  = (const float*)d_in[5];
    const float* w2  = (const float*)d_in[6];
    const float* w3  = (const float*)d_in[7];
    const float* wc  = (const float*)d_in[8];
    const float* bias= (const float*)d_in[9];
    float* out = (float*)d_out;

    char* ws = (char*)d_ws;
    const size_t WBASE = (1u<<20);
    const size_t FB = 67699712ull;                 // padded fea buffer + 64KB tail
    const size_t NEED_A = WBASE + 4*FB;
    const size_t NEED_B = WBASE + 2*FB;
    if (ws_size < NEED_B) return;

    float* ws_ch = (float*)ws;
    f16* bpk0 = (f16*)(ws + 4096);
    f16* bpkL = (f16*)(ws + 4096 + 73728);
    f16* wcpk = (f16*)(ws + 4096 + 73728 + 442368);

    k_prep_ch<<<1, 256, 0, stream>>>(gum, chm, ws_ch, out + 33554432);
    k_pack<<<1072, 256, 0, stream>>>(w0, w1, w2, w3, wc, ws_ch, bpk0, bpkL, wcpk);

    dim3 gcv(4, 512/ROWS, 2);   // conv: 128-px strip x 8 streamed rows
    dim3 gca(2, 512, 2);        // collect_all: 256-px tiles
    dim3 gcf(8, 512, 2);        // fallback collect: 64-px tiles

    if (ws_size >= NEED_A) {
        f16* R0 = (f16*)(ws + WBASE);              // fea4 (conv3 output)
        f16* R1 = (f16*)(ws + WBASE + FB);
        f16* R2 = (f16*)(ws + WBASE + 2*FB);
        f16* R3 = (f16*)(ws + WBASE + 3*FB);
        k_guard<<<129, 256, 0, stream>>>(R1);
        k_guard<<<129, 256, 0, stream>>>(R2);
        k_guard<<<129, 256, 0, stream>>>(R3);
        k_conv<0><<<gcv, 256, 0, stream>>>(x0, R1, bpk0,          ws_ch + 0,   spa);
        k_conv<1><<<gcv, 256, 0, stream>>>(R1, R2, bpkL + 0,      ws_ch + 128, spa);
        k_conv<1><<<gcv, 256, 0, stream>>>(R2, R3, bpkL + 73728,  ws_ch + 256, spa);
        k_conv<1><<<gcv, 256, 0, stream>>>(R3, R0, bpkL + 147456, ws_ch + 384, spa);
        k_collect_all<<<gca, 256, 0, stream>>>(R1, R2, R3, R0, wcpk, bias, out);
    } else {
        f16* P0 = (f16*)(ws + WBASE);
        f16* P1 = (f16*)(ws + WBASE + FB);
        k_guard<<<129, 256, 0, stream>>>(P0);
        k_guard<<<129, 256, 0, stream>>>(P1);
        k_conv<0><<<gcv, 256, 0, stream>>>(x0, P1, bpk0,          ws_ch + 0,   spa);
        k_collect<true ><<<gcf, 256, 0, stream>>>(P1, wcpk + 0,     bias, out);
        k_conv<1><<<gcv, 256, 0, stream>>>(P1, P0, bpkL + 0,      ws_ch + 128, spa);
        k_collect<false><<<gcf, 256, 0, stream>>>(P0, wcpk + 4096,  bias, out);
        k_conv<1><<<gcv, 256, 0, stream>>>(P0, P1, bpkL + 73728,  ws_ch + 256, spa);
        k_collect<false><<<gcf, 256, 0, stream>>>(P1, wcpk + 8192,  bias, out);
        k_conv<1><<<gcv, 256, 0, stream>>>(P1, P0, bpkL + 147456, ws_ch + 384, spa);
        k_collect<false><<<gcf, 256, 0, stream>>>(P0, wcpk + 12288, bias, out);
    }
}

// Round 16
// 353.490 us; speedup vs baseline: 2.3990x; 2.3990x over previous
//
#include <hip/hip_runtime.h>
#include <hip/hip_fp16.h>

#define BB 2
#define HH 512
#define WW 512
#define CC 64
#define PW 514

typedef _Float16 f16;
typedef _Float16 f16x8 __attribute__((ext_vector_type(8)));
typedef float f32x4 __attribute__((ext_vector_type(4)));

static __device__ __forceinline__ f16x8 zero_f16x8() {
    f16x8 z = {(f16)0,(f16)0,(f16)0,(f16)0,(f16)0,(f16)0,(f16)0,(f16)0};
    return z;
}

static __device__ __forceinline__ f16x8 cvt_pair(f32x4 a, f32x4 b) {
    f16x8 o;
    o[0]=(f16)a[0]; o[1]=(f16)a[1]; o[2]=(f16)a[2]; o[3]=(f16)a[3];
    o[4]=(f16)b[0]; o[5]=(f16)b[1]; o[6]=(f16)b[2]; o[7]=(f16)b[3];
    return o;
}

// ---------------------------------------------------------------- prep: ch
__global__ void k_prep_ch(const float* __restrict__ gum, const float* __restrict__ chm,
                          float* __restrict__ ws_ch, float* __restrict__ out_ch) {
    int t = threadIdx.x;           // 256 threads, one (l,c) pair each
    int l = t >> 6, c = t & 63;
    float u0 = gum[(l*2+0)*64+c], u1 = gum[(l*2+1)*64+c];
    u0 = fminf(fmaxf(u0, 1e-10f), 1.0f);
    u1 = fminf(fmaxf(u1, 1e-10f), 1.0f);
    float a0 = chm[(l*2+0)*64+c] - logf(-logf(u0));   // TAU = 1
    float a1 = chm[(l*2+1)*64+c] - logf(-logf(u1));
    float m = fmaxf(a0, a1);
    float e0 = expf(a0-m), e1 = expf(a1-m);
    float s = e0 + e1;
    float c0 = e0/s, c1 = e1/s;
    ws_ch[(l*2+0)*64+c] = c0;  ws_ch[(l*2+1)*64+c] = c1;
    out_ch[(l*2+0)*64+c] = c0; out_ch[(l*2+1)*64+c] = c1;
}

// ------------------------------------------------------------ weight packing
// Bpk layout: [kb][nbTot][lane][8] f16, fragment-direct for mfma 16x16x32.
__global__ void k_pack(const float* __restrict__ w0, const float* __restrict__ w1,
                       const float* __restrict__ w2, const float* __restrict__ w3,
                       const float* __restrict__ wc, const float* __restrict__ ch,
                       f16* __restrict__ bpk0, f16* __restrict__ bpkL, f16* __restrict__ wcpk) {
    int idx = blockIdx.x * 256 + threadIdx.x;
    if (idx < 36864) {
        int j = idx & 7, lane = (idx>>3)&63, nb = (idx>>9)&3, kb = idx>>11;
        int k = kb*32 + (lane>>4)*8 + j;
        int tap = k>>6, ci = k&63;
        int co = nb*16 + (lane&15);
        bpk0[idx] = (f16)w0[(tap*64+ci)*64+co];
    } else if (idx < 36864 + 221184) {
        int i2 = idx - 36864;
        int l = i2 / 73728;               // 0..2 -> layer l+1, masks from ch[l]
        int r = i2 % 73728;
        int j = r&7, lane=(r>>3)&63, nb=(r>>9)&7, kb=r>>12;
        int k = kb*32 + (lane>>4)*8 + j;
        int tap = k>>6, ci = k&63;
        int copr = nb*16 + (lane&15);     // 0..127, [0:64)=dense, [64:128)=sparse
        int co = copr & 63;
        const float* w = (l==0)? w1 : (l==1)? w2 : w3;
        float scale = (copr < 64) ? ch[(l*2+0)*64+ci] : ch[(l*2+1)*64+ci];
        bpkL[i2] = (f16)(w[(tap*64+ci)*64+co] * scale);
    } else if (idx < 36864 + 221184 + 16384) {
        int i3 = idx - (36864 + 221184);
        int j=i3&7, lane=(i3>>3)&63, nb=(i3>>9)&3, kb=(i3>>11)&1, l=i3>>12;
        int k = kb*32 + (lane>>4)*8 + j;
        int n = nb*16 + (lane&15);
        wcpk[i3] = (f16)wc[(l*64+k)*64+n];
    }
}

// ---------------------------- zero the guard ring of fea buffers (3 at once)
__global__ void k_guard(f16* __restrict__ b1, f16* __restrict__ b2, f16* __restrict__ b3) {
    f16* buf = (blockIdx.y == 0) ? b1 : (blockIdx.y == 1) ? b2 : b3;
    int idx = blockIdx.x*256 + threadIdx.x;       // 16B units
    const int TOT = 2*2052*8;
    if (idx >= TOT) return;
    int c8 = idx & 7, g = idx >> 3;
    int b = g / 2052, r = g % 2052;
    int hp, wp;
    if      (r < 514)  { hp = 0;        wp = r; }
    else if (r < 1028) { hp = 513;      wp = r-514; }
    else if (r < 1540) { hp = r-1027;   wp = 0; }
    else               { hp = r-1539;   wp = 513; }
    *(f16x8*)(buf + ((size_t)(b*PW+hp)*PW + wp)*64 + c8*8) = zero_f16x8();
}

// ------------------------------------------------------------------- conv
// Block: 4 waves = 2 rows (wr) x 2 col-halves (wn); tile 128 px x 2 rows.
// MODE 0: input = RAW f32 x0 [B][512][512][64]; staging fused: two batches
//   of 9 f32x4-pair loads -> cvt -> ds_write (swizzled layout), one barrier.
// MODE 1: input padded f16; global_load_lds staging split in two phases
//   (second phase drains at kb==5 under MFMAs).
// A and B register-double-buffered across the 18 k-blocks; MFMAs under
// setprio(1). LDS sub-slots XOR-swizzled (rule 21): cblk = sub ^ srel.
// MODE 0: N=64,  out = relu(conv * (cs*spa + cd))
// MODE 1: N=128, out = relu(D*(cs*spa+cd) + S*spa)
template<int MODE>
__global__ __launch_bounds__(256, 2) void k_conv(const void* __restrict__ in_, f16* __restrict__ out,
        const f16* __restrict__ bpk, const float* __restrict__ ch_l,
        const float* __restrict__ spa) {
    constexpr int NBT = (MODE==0) ? 4 : 8;
    constexpr int NF  = (MODE==0) ? 2 : 4;
    __shared__ f16 smem[4*136*64];                 // 69632 B
    const int wt = blockIdx.x, hb = blockIdx.y, b = blockIdx.z;
    const int h0 = hb*2;
    const int tid = threadIdx.x, lane = tid & 63, wid = tid >> 6;
    const int px0 = wt*128;
    const int sub  = lane & 7;
    const int srel = lane >> 3;
    const int cblk = sub ^ srel;                   // s&7 == srel for s=i*8+srel

    if (MODE == 0) {
        // ---- fused staging from raw f32: all 4 rows, two register batches ----
        const float* inF = (const float*)in_;
        #pragma unroll
        for (int half = 0; half < 2; ++half) {
            const int J0 = half ? 9 : 0;
            const int JN = half ? 8 : 9;
            f32x4 v0[9], v1[9];
            bool ok[9];
            int dst[9];
            #pragma unroll
            for (int t = 0; t < JN; ++t) {
                int j = (J0 + t)*4 + wid;          // 0..67
                int r = j / 17, i = j % 17;
                int s = i*8 + srel;
                int hin = h0 + r - 1;
                int win = px0 + s - 1;
                ok[t] = ((unsigned)hin < HH) && ((unsigned)win < WW);
                dst[t] = r*17408 + i*1024 + lane*16;
                if (ok[t]) {
                    const f32x4* p = (const f32x4*)(inF + (((size_t)(b*HH + hin)*WW + win)*CC + cblk*8));
                    v0[t] = p[0];
                    v1[t] = p[1];
                }
            }
            #pragma unroll
            for (int t = 0; t < JN; ++t) {
                f16x8 o = ok[t] ? cvt_pair(v0[t], v1[t]) : zero_f16x8();
                if ((J0 + t)*4 + wid < 68)
                    *(f16x8*)((char*)smem + dst[t]) = o;
            }
        }
        __syncthreads();
    } else {
        const f16* inH = (const f16*)in_;
        // ---- stage phase 1: rows 0,1 (j = 0..33) ----
        #pragma unroll
        for (int jj = 0; jj < 9; ++jj) {
            int j = jj*4 + wid;
            if (j < 34) {
                int r = j / 17, i = j % 17;
                int s = i*8 + srel;
                const f16* src = inH + ((size_t)(b*PW + h0 + r)*PW + (px0 + s))*64 + cblk*8;
                __builtin_amdgcn_global_load_lds(
                    (const __attribute__((address_space(1))) uint32_t*)src,
                    (__attribute__((address_space(3))) uint32_t*)
                        ((char*)smem + r*17408 + i*1024),
                    16, 0, 0);
            }
        }
        __syncthreads();
        // ---- stage phase 2: rows 2,3 (j = 34..67), drained at kb==5 ----
        #pragma unroll
        for (int jj = 0; jj < 9; ++jj) {
            int j = 34 + jj*4 + wid;
            if (j < 68) {
                int r = j / 17, i = j % 17;
                int s = i*8 + srel;
                const f16* src = inH + ((size_t)(b*PW + h0 + r)*PW + (px0 + s))*64 + cblk*8;
                __builtin_amdgcn_global_load_lds(
                    (const __attribute__((address_space(1))) uint32_t*)src,
                    (__attribute__((address_space(3))) uint32_t*)
                        ((char*)smem + r*17408 + i*1024),
                    16, 0, 0);
            }
        }
    }

    const int wr = wid >> 1, wn = wid & 1;
    const int lrow = lane & 15, q = lane >> 4;
    const char* smw = (const char*)smem + wr*17408;   // wave's row-0 base

    // per-lane LDS read offsets: slot s = mf*16+lrow+dxi ; s&7 = (lrow+dxi)&7
    int sb[8][3], po[2][3];
    #pragma unroll
    for (int dxi = 0; dxi < 3; ++dxi) {
        int m7 = (lrow + dxi) & 7;
        po[0][dxi] = ((q)     ^ m7) * 16;
        po[1][dxi] = ((4 + q) ^ m7) * 16;
        #pragma unroll
        for (int mf = 0; mf < 8; ++mf)
            sb[mf][dxi] = (mf*16 + lrow + dxi) * 128;
    }

    f32x4 acc[8][NF];
    #pragma unroll
    for (int i=0;i<8;i++)
        #pragma unroll
        for (int j=0;j<NF;j++) { f32x4 z = {0.f,0.f,0.f,0.f}; acc[i][j] = z; }

    int nbIdx[4];
    nbIdx[0]=wn*2; nbIdx[1]=wn*2+1; nbIdx[2]=wn*2+4; nbIdx[3]=wn*2+5;

    const f16* blane = bpk + (size_t)lane*8;       // + kb*NBT*512 + nb*512

    f16x8 acur[8], anxt[8], bcur[NF], bnxt[NF];
    #pragma unroll
    for (int nf=0; nf<NF; ++nf)
        bcur[nf] = *reinterpret_cast<const f16x8*>(blane + (size_t)nbIdx[nf]*512);
    #pragma unroll
    for (int mf=0; mf<8; ++mf)
        acur[mf] = *(const f16x8*)(smw + sb[mf][0] + po[0][0]);

    #pragma unroll
    for (int kb = 0; kb < 18; ++kb) {
        if (MODE == 1 && kb == 5) __syncthreads(); // rows 2,3 ready; drained under kb0-4
        if (kb < 17) {
            const int kn = kb + 1;
            const int rn = kn/6, dxin = (kn%6)/2, halfn = kn & 1;
            #pragma unroll
            for (int nf=0; nf<NF; ++nf)
                bnxt[nf] = *reinterpret_cast<const f16x8*>(blane + (size_t)(kn*NBT + nbIdx[nf])*512);
            #pragma unroll
            for (int mf=0; mf<8; ++mf)
                anxt[mf] = *(const f16x8*)(smw + rn*17408 + sb[mf][dxin] + po[halfn][dxin]);
        }
        __builtin_amdgcn_s_setprio(1);
        #pragma unroll
        for (int nf=0; nf<NF; ++nf) {
            #pragma unroll
            for (int mf=0; mf<8; ++mf)
                acc[mf][nf] = __builtin_amdgcn_mfma_f32_16x16x32_f16(acur[mf], bcur[nf], acc[mf][nf], 0,0,0);
        }
        __builtin_amdgcn_s_setprio(0);
        #pragma unroll
        for (int nf=0; nf<NF; ++nf) bcur[nf] = bnxt[nf];
        #pragma unroll
        for (int mf=0; mf<8; ++mf) acur[mf] = anxt[mf];
    }

    const float* cd = ch_l;
    const float* cs = ch_l + 64;
    const int h = h0 + wr;
    const size_t sparow = (size_t)(b*HH + h)*WW;
    const size_t outrow = (size_t)(b*PW + h + 1)*PW + 1;
    #pragma unroll
    for (int mf=0; mf<8; ++mf) {
        const int pixb = mf*16 + q*4;
        f32x4 sp4 = *(const f32x4*)(spa + sparow + px0 + pixb);
        float sp[4] = {sp4[0], sp4[1], sp4[2], sp4[3]};
        #pragma unroll
        for (int nf2=0; nf2<2; ++nf2) {
            int co = wn*32 + nf2*16 + lrow;
            float vcd = cd[co], vcs = cs[co];
            #pragma unroll
            for (int r=0; r<4; ++r) {
                float v;
                if (MODE==0) v = acc[mf][nf2][r] * (vcs*sp[r] + vcd);
                else         v = acc[mf][nf2][r] * (vcs*sp[r] + vcd) + acc[mf][nf2+2][r] * sp[r];
                v = fmaxf(v, 0.f);
                out[(outrow + px0 + pixb + r)*64 + co] = (f16)v;
            }
        }
    }
}

// --------------------------------------------------- collect (single pass)
// out[p,co] = sum_l fea_l[p,:] @ Wc_l + bias.  K = 256. Padded f16 inputs.
// mfma(W, X, C) -> transposed C -> f32x4 (16B) plain stores.
__global__ __launch_bounds__(256) void k_collect_all(
        const f16* __restrict__ f0, const f16* __restrict__ f1,
        const f16* __restrict__ f2, const f16* __restrict__ f3,
        const f16* __restrict__ wcpk, const float* __restrict__ bias,
        float* __restrict__ out) {
    const int wt = blockIdx.x, h = blockIdx.y, b = blockIdx.z;
    const int tid = threadIdx.x;
    const int lane = tid & 63, wid = tid >> 6;
    const int lrow = lane & 15, lk = (lane>>4)*8;
    const size_t inrow  = (size_t)(b*PW + h + 1)*PW + 1;
    const size_t outrow = (size_t)(b*HH + h)*WW;
    const int px0 = wt*256 + wid*64;

    const f16* feas[4] = {f0, f1, f2, f3};

    f32x4 acc[4][4];
    #pragma unroll
    for (int i=0;i<4;i++)
        #pragma unroll
        for (int j=0;j<4;j++) { f32x4 z = {0.f,0.f,0.f,0.f}; acc[i][j] = z; }

    #pragma unroll
    for (int kb=0; kb<8; ++kb) {
        const f16* fl = feas[kb>>1];
        f16x8 a[4];
        #pragma unroll
        for (int mf=0; mf<4; ++mf)
            a[mf] = *reinterpret_cast<const f16x8*>(fl + (inrow + px0 + mf*16 + lrow)*64 + (kb&1)*32 + lk);
        #pragma unroll
        for (int nf=0; nf<4; ++nf) {
            f16x8 bb = *reinterpret_cast<const f16x8*>(wcpk + ((size_t)(kb*4 + nf)*64 + lane)*8);
            #pragma unroll
            for (int mf=0; mf<4; ++mf)
                acc[mf][nf] = __builtin_amdgcn_mfma_f32_16x16x32_f16(bb, a[mf], acc[mf][nf], 0,0,0);
        }
    }
    const int q = lane >> 4;
    #pragma unroll
    for (int mf=0; mf<4; ++mf) {
        const int pix = px0 + mf*16 + lrow;
        float* orow = out + (outrow + pix)*CC;
        #pragma unroll
        for (int nf=0; nf<4; ++nf) {
            const int co0 = nf*16 + q*4;
            f32x4 b4 = *(const f32x4*)(bias + co0);
            *(f32x4*)(orow + co0) = acc[mf][nf] + b4;
        }
    }
}

// --------------------------------------- collect fallback (per-layer RMW)
template<bool FIRST>
__global__ __launch_bounds__(256) void k_collect(const f16* __restrict__ fea,
        const f16* __restrict__ wcpk_l, const float* __restrict__ bias,
        float* __restrict__ out) {
    const int wt = blockIdx.x, h = blockIdx.y, b = blockIdx.z;
    const int tid = threadIdx.x;
    const int lane = tid & 63, wid = tid >> 6;
    const int lrow = lane & 15, lk = (lane>>4)*8;
    const size_t inrow  = (size_t)(b*PW + h + 1)*PW + 1;
    const size_t outrow = (size_t)(b*HH + h)*WW;
    const int px0 = wt*64 + wid*16;

    f32x4 acc[4];
    #pragma unroll
    for (int j=0;j<4;j++) { f32x4 z = {0.f,0.f,0.f,0.f}; acc[j] = z; }

    #pragma unroll
    for (int kb=0; kb<2; ++kb) {
        f16x8 a = *reinterpret_cast<const f16x8*>(fea + (inrow + px0 + lrow)*64 + kb*32 + lk);
        #pragma unroll
        for (int nf=0; nf<4; ++nf) {
            f16x8 bb = *reinterpret_cast<const f16x8*>(wcpk_l + ((size_t)(kb*4 + nf)*64 + lane)*8);
            acc[nf] = __builtin_amdgcn_mfma_f32_16x16x32_f16(bb, a, acc[nf], 0,0,0);
        }
    }
    const int q = lane >> 4;
    const int pix = px0 + lrow;
    float* orow = out + (outrow + pix)*CC;
    #pragma unroll
    for (int nf=0; nf<4; ++nf) {
        const int co0 = nf*16 + q*4;
        f32x4 v = acc[nf];
        #pragma unroll
        for (int r=0;r<4;++r) {
            float x = v[r];
            if (FIRST) x += bias[co0+r];
            else       x += orow[co0+r];
            orow[co0+r] = x;
        }
    }
}

// ------------------------------------------------------------------ launch
extern "C" void kernel_launch(void* const* d_in, const int* in_sizes, int n_in,
                              void* d_out, int out_size, void* d_ws, size_t ws_size,
                              hipStream_t stream) {
    const float* x0  = (const float*)d_in[0];
    const float* spa = (const float*)d_in[1];
    const float* gum = (const float*)d_in[2];
    const float* chm = (const float*)d_in[3];
    const float* w0  = (const float*)d_in[4];
    const float* w1  = (const float*)d_in[5];
    const float* w2  = (const float*)d_in[6];
    const float* w3  = (const float*)d_in[7];
    const float* wc  = (const float*)d_in[8];
    const float* bias= (const float*)d_in[9];
    float* out = (float*)d_out;

    char* ws = (char*)d_ws;
    const size_t WBASE = (1u<<20);
    const size_t FB = 67699712ull;                 // padded fea buffer + 64KB tail
    const size_t NEED_A = WBASE + 4*FB;
    const size_t NEED_B = WBASE + 2*FB;
    if (ws_size < NEED_B) return;

    float* ws_ch = (float*)ws;
    f16* bpk0 = (f16*)(ws + 4096);
    f16* bpkL = (f16*)(ws + 4096 + 73728);
    f16* wcpk = (f16*)(ws + 4096 + 73728 + 442368);

    k_prep_ch<<<1, 256, 0, stream>>>(gum, chm, ws_ch, out + 33554432);
    k_pack<<<1072, 256, 0, stream>>>(w0, w1, w2, w3, wc, ws_ch, bpk0, bpkL, wcpk);

    dim3 gcv(4, 256, 2);    // conv blocks: 128 px x 2 rows, 256 threads
    dim3 gca(2, 512, 2);    // collect_all: 256-px tiles
    dim3 gcf(8, 512, 2);    // fallback collect: 64-px tiles
    dim3 ggd(129, 3, 1);    // guard: 3 buffers in one launch

    if (ws_size >= NEED_A) {
        f16* R0 = (f16*)(ws + WBASE);              // fea4 (conv3 output)
        f16* R1 = (f16*)(ws + WBASE + FB);
        f16* R2 = (f16*)(ws + WBASE + 2*FB);
        f16* R3 = (f16*)(ws + WBASE + 3*FB);
        k_guard<<<ggd, 256, 0, stream>>>(R1, R2, R3);
        k_conv<0><<<gcv, 256, 0, stream>>>(x0, R1, bpk0,          ws_ch + 0,   spa);
        k_conv<1><<<gcv, 256, 0, stream>>>(R1, R2, bpkL + 0,      ws_ch + 128, spa);
        k_conv<1><<<gcv, 256, 0, stream>>>(R2, R3, bpkL + 73728,  ws_ch + 256, spa);
        k_conv<1><<<gcv, 256, 0, stream>>>(R3, R0, bpkL + 147456, ws_ch + 384, spa);
        k_collect_all<<<gca, 256, 0, stream>>>(R1, R2, R3, R0, wcpk, bias, out);
    } else {
        f16* P0 = (f16*)(ws + WBASE);
        f16* P1 = (f16*)(ws + WBASE + FB);
        k_guard<<<ggd, 256, 0, stream>>>(P0, P1, P0);
        k_conv<0><<<gcv, 256, 0, stream>>>(x0, P1, bpk0,          ws_ch + 0,   spa);
        k_collect<true ><<<gcf, 256, 0, stream>>>(P1, wcpk + 0,     bias, out);
        k_conv<1><<<gcv, 256, 0, stream>>>(P1, P0, bpkL + 0,      ws_ch + 128, spa);
        k_collect<false><<<gcf, 256, 0, stream>>>(P0, wcpk + 4096,  bias, out);
        k_conv<1><<<gcv, 256, 0, stream>>>(P0, P1, bpkL + 73728,  ws_ch + 256, spa);
        k_collect<false><<<gcf, 256, 0, stream>>>(P1, wcpk + 8192,  bias, out);
        k_conv<1><<<gcv, 256, 0, stream>>>(P1, P0, bpkL + 147456, ws_ch + 384, spa);
        k_collect<false><<<gcf, 256, 0, stream>>>(P0, wcpk + 12288, bias, out);
    }
}

// Round 17
// 347.034 us; speedup vs baseline: 2.4437x; 1.0186x over previous
//
#include <hip/hip_runtime.h>
#include <hip/hip_fp16.h>

#define BB 2
#define HH 512
#define WW 512
#define CC 64
#define PW 514

typedef _Float16 f16;
typedef _Float16 f16x8 __attribute__((ext_vector_type(8)));
typedef float f32x4 __attribute__((ext_vector_type(4)));

static __device__ __forceinline__ f16x8 zero_f16x8() {
    f16x8 z = {(f16)0,(f16)0,(f16)0,(f16)0,(f16)0,(f16)0,(f16)0,(f16)0};
    return z;
}

static __device__ __forceinline__ f16x8 cvt_pair(f32x4 a, f32x4 b) {
    f16x8 o;
    o[0]=(f16)a[0]; o[1]=(f16)a[1]; o[2]=(f16)a[2]; o[3]=(f16)a[3];
    o[4]=(f16)b[0]; o[5]=(f16)b[1]; o[6]=(f16)b[2]; o[7]=(f16)b[3];
    return o;
}

// ---------------------------------------------------------------- prep: ch
__global__ void k_prep_ch(const float* __restrict__ gum, const float* __restrict__ chm,
                          float* __restrict__ ws_ch, float* __restrict__ out_ch) {
    int t = threadIdx.x;           // 256 threads, one (l,c) pair each
    int l = t >> 6, c = t & 63;
    float u0 = gum[(l*2+0)*64+c], u1 = gum[(l*2+1)*64+c];
    u0 = fminf(fmaxf(u0, 1e-10f), 1.0f);
    u1 = fminf(fmaxf(u1, 1e-10f), 1.0f);
    float a0 = chm[(l*2+0)*64+c] - logf(-logf(u0));   // TAU = 1
    float a1 = chm[(l*2+1)*64+c] - logf(-logf(u1));
    float m = fmaxf(a0, a1);
    float e0 = expf(a0-m), e1 = expf(a1-m);
    float s = e0 + e1;
    float c0 = e0/s, c1 = e1/s;
    ws_ch[(l*2+0)*64+c] = c0;  ws_ch[(l*2+1)*64+c] = c1;
    out_ch[(l*2+0)*64+c] = c0; out_ch[(l*2+1)*64+c] = c1;
}

// ------------------------------------------------------------ weight packing
// Bpk layout: [kb][nbTot][lane][8] f16, fragment-direct for mfma 16x16x32.
__global__ void k_pack(const float* __restrict__ w0, const float* __restrict__ w1,
                       const float* __restrict__ w2, const float* __restrict__ w3,
                       const float* __restrict__ wc, const float* __restrict__ ch,
                       f16* __restrict__ bpk0, f16* __restrict__ bpkL, f16* __restrict__ wcpk) {
    int idx = blockIdx.x * 256 + threadIdx.x;
    if (idx < 36864) {
        int j = idx & 7, lane = (idx>>3)&63, nb = (idx>>9)&3, kb = idx>>11;
        int k = kb*32 + (lane>>4)*8 + j;
        int tap = k>>6, ci = k&63;
        int co = nb*16 + (lane&15);
        bpk0[idx] = (f16)w0[(tap*64+ci)*64+co];
    } else if (idx < 36864 + 221184) {
        int i2 = idx - 36864;
        int l = i2 / 73728;               // 0..2 -> layer l+1, masks from ch[l]
        int r = i2 % 73728;
        int j = r&7, lane=(r>>3)&63, nb=(r>>9)&7, kb=r>>12;
        int k = kb*32 + (lane>>4)*8 + j;
        int tap = k>>6, ci = k&63;
        int copr = nb*16 + (lane&15);     // 0..127, [0:64)=dense, [64:128)=sparse
        int co = copr & 63;
        const float* w = (l==0)? w1 : (l==1)? w2 : w3;
        float scale = (copr < 64) ? ch[(l*2+0)*64+ci] : ch[(l*2+1)*64+ci];
        bpkL[i2] = (f16)(w[(tap*64+ci)*64+co] * scale);
    } else if (idx < 36864 + 221184 + 16384) {
        int i3 = idx - (36864 + 221184);
        int j=i3&7, lane=(i3>>3)&63, nb=(i3>>9)&3, kb=(i3>>11)&1, l=i3>>12;
        int k = kb*32 + (lane>>4)*8 + j;
        int n = nb*16 + (lane&15);
        wcpk[i3] = (f16)wc[(l*64+k)*64+n];
    }
}

// ---------------------------- zero the guard ring of fea buffers (3 at once)
__global__ void k_guard(f16* __restrict__ b1, f16* __restrict__ b2, f16* __restrict__ b3) {
    f16* buf = (blockIdx.y == 0) ? b1 : (blockIdx.y == 1) ? b2 : b3;
    int idx = blockIdx.x*256 + threadIdx.x;       // 16B units
    const int TOT = 2*2052*8;
    if (idx >= TOT) return;
    int c8 = idx & 7, g = idx >> 3;
    int b = g / 2052, r = g % 2052;
    int hp, wp;
    if      (r < 514)  { hp = 0;        wp = r; }
    else if (r < 1028) { hp = 513;      wp = r-514; }
    else if (r < 1540) { hp = r-1027;   wp = 0; }
    else               { hp = r-1539;   wp = 513; }
    *(f16x8*)(buf + ((size_t)(b*PW+hp)*PW + wp)*64 + c8*8) = zero_f16x8();
}

// ------------------------------------------------------------------- conv
// Block: 4 waves = 2 rows (wr) x 2 col-halves (wn); tile 128 px x 2 rows.
// XCD-AWARE SWIZZLE (T1): flat grid 2048; xcd = bid&7 selects the (b,wt)
// column-strip, hb = bid>>3 walks down it. Each XCD owns one full strip ->
// vertically adjacent blocks (sharing 2 of 4 staged rows) are ALWAYS on the
// same XCD's L2, and the ~32 resident blocks/XCD cover a contiguous band.
// MODE 0: input = RAW f32 x0 [B][512][512][64]; staging fused: two batches
//   of 9 f32x4-pair loads -> cvt -> ds_write (swizzled layout), one barrier.
// MODE 1: input padded f16; global_load_lds staging split in two phases
//   (second phase drains at kb==5 under MFMAs).
// A and B register-double-buffered across the 18 k-blocks; MFMAs under
// setprio(1). LDS sub-slots XOR-swizzled (rule 21): cblk = sub ^ srel.
// MODE 0: N=64,  out = relu(conv * (cs*spa + cd))
// MODE 1: N=128, out = relu(D*(cs*spa+cd) + S*spa)
template<int MODE>
__global__ __launch_bounds__(256, 2) void k_conv(const void* __restrict__ in_, f16* __restrict__ out,
        const f16* __restrict__ bpk, const float* __restrict__ ch_l,
        const float* __restrict__ spa) {
    constexpr int NBT = (MODE==0) ? 4 : 8;
    constexpr int NF  = (MODE==0) ? 2 : 4;
    __shared__ f16 smem[4*136*64];                 // 69632 B
    const int bid = blockIdx.x;
    const int xcd = bid & 7;                       // consecutive bids round-robin XCDs
    const int wt  = xcd & 3;
    const int b   = xcd >> 2;
    const int hb  = bid >> 3;                      // 0..255, contiguous per XCD
    const int h0 = hb*2;
    const int tid = threadIdx.x, lane = tid & 63, wid = tid >> 6;
    const int px0 = wt*128;
    const int sub  = lane & 7;
    const int srel = lane >> 3;
    const int cblk = sub ^ srel;                   // s&7 == srel for s=i*8+srel

    if (MODE == 0) {
        // ---- fused staging from raw f32: all 4 rows, two register batches ----
        const float* inF = (const float*)in_;
        #pragma unroll
        for (int half = 0; half < 2; ++half) {
            const int J0 = half ? 9 : 0;
            const int JN = half ? 8 : 9;
            f32x4 v0[9], v1[9];
            bool ok[9];
            int dst[9];
            #pragma unroll
            for (int t = 0; t < JN; ++t) {
                int j = (J0 + t)*4 + wid;          // 0..67
                int r = j / 17, i = j % 17;
                int s = i*8 + srel;
                int hin = h0 + r - 1;
                int win = px0 + s - 1;
                ok[t] = ((unsigned)hin < HH) && ((unsigned)win < WW);
                dst[t] = r*17408 + i*1024 + lane*16;
                if (ok[t]) {
                    const f32x4* p = (const f32x4*)(inF + (((size_t)(b*HH + hin)*WW + win)*CC + cblk*8));
                    v0[t] = p[0];
                    v1[t] = p[1];
                }
            }
            #pragma unroll
            for (int t = 0; t < JN; ++t) {
                f16x8 o = ok[t] ? cvt_pair(v0[t], v1[t]) : zero_f16x8();
                if ((J0 + t)*4 + wid < 68)
                    *(f16x8*)((char*)smem + dst[t]) = o;
            }
        }
        __syncthreads();
    } else {
        const f16* inH = (const f16*)in_;
        // ---- stage phase 1: rows 0,1 (j = 0..33) ----
        #pragma unroll
        for (int jj = 0; jj < 9; ++jj) {
            int j = jj*4 + wid;
            if (j < 34) {
                int r = j / 17, i = j % 17;
                int s = i*8 + srel;
                const f16* src = inH + ((size_t)(b*PW + h0 + r)*PW + (px0 + s))*64 + cblk*8;
                __builtin_amdgcn_global_load_lds(
                    (const __attribute__((address_space(1))) uint32_t*)src,
                    (__attribute__((address_space(3))) uint32_t*)
                        ((char*)smem + r*17408 + i*1024),
                    16, 0, 0);
            }
        }
        __syncthreads();
        // ---- stage phase 2: rows 2,3 (j = 34..67), drained at kb==5 ----
        #pragma unroll
        for (int jj = 0; jj < 9; ++jj) {
            int j = 34 + jj*4 + wid;
            if (j < 68) {
                int r = j / 17, i = j % 17;
                int s = i*8 + srel;
                const f16* src = inH + ((size_t)(b*PW + h0 + r)*PW + (px0 + s))*64 + cblk*8;
                __builtin_amdgcn_global_load_lds(
                    (const __attribute__((address_space(1))) uint32_t*)src,
                    (__attribute__((address_space(3))) uint32_t*)
                        ((char*)smem + r*17408 + i*1024),
                    16, 0, 0);
            }
        }
    }

    const int wr = wid >> 1, wn = wid & 1;
    const int lrow = lane & 15, q = lane >> 4;
    const char* smw = (const char*)smem + wr*17408;   // wave's row-0 base

    // per-lane LDS read offsets: slot s = mf*16+lrow+dxi ; s&7 = (lrow+dxi)&7
    int sb[8][3], po[2][3];
    #pragma unroll
    for (int dxi = 0; dxi < 3; ++dxi) {
        int m7 = (lrow + dxi) & 7;
        po[0][dxi] = ((q)     ^ m7) * 16;
        po[1][dxi] = ((4 + q) ^ m7) * 16;
        #pragma unroll
        for (int mf = 0; mf < 8; ++mf)
            sb[mf][dxi] = (mf*16 + lrow + dxi) * 128;
    }

    f32x4 acc[8][NF];
    #pragma unroll
    for (int i=0;i<8;i++)
        #pragma unroll
        for (int j=0;j<NF;j++) { f32x4 z = {0.f,0.f,0.f,0.f}; acc[i][j] = z; }

    int nbIdx[4];
    nbIdx[0]=wn*2; nbIdx[1]=wn*2+1; nbIdx[2]=wn*2+4; nbIdx[3]=wn*2+5;

    const f16* blane = bpk + (size_t)lane*8;       // + kb*NBT*512 + nb*512

    f16x8 acur[8], anxt[8], bcur[NF], bnxt[NF];
    #pragma unroll
    for (int nf=0; nf<NF; ++nf)
        bcur[nf] = *reinterpret_cast<const f16x8*>(blane + (size_t)nbIdx[nf]*512);
    #pragma unroll
    for (int mf=0; mf<8; ++mf)
        acur[mf] = *(const f16x8*)(smw + sb[mf][0] + po[0][0]);

    #pragma unroll
    for (int kb = 0; kb < 18; ++kb) {
        if (MODE == 1 && kb == 5) __syncthreads(); // rows 2,3 ready; drained under kb0-4
        if (kb < 17) {
            const int kn = kb + 1;
            const int rn = kn/6, dxin = (kn%6)/2, halfn = kn & 1;
            #pragma unroll
            for (int nf=0; nf<NF; ++nf)
                bnxt[nf] = *reinterpret_cast<const f16x8*>(blane + (size_t)(kn*NBT + nbIdx[nf])*512);
            #pragma unroll
            for (int mf=0; mf<8; ++mf)
                anxt[mf] = *(const f16x8*)(smw + rn*17408 + sb[mf][dxin] + po[halfn][dxin]);
        }
        __builtin_amdgcn_s_setprio(1);
        #pragma unroll
        for (int nf=0; nf<NF; ++nf) {
            #pragma unroll
            for (int mf=0; mf<8; ++mf)
                acc[mf][nf] = __builtin_amdgcn_mfma_f32_16x16x32_f16(acur[mf], bcur[nf], acc[mf][nf], 0,0,0);
        }
        __builtin_amdgcn_s_setprio(0);
        #pragma unroll
        for (int nf=0; nf<NF; ++nf) bcur[nf] = bnxt[nf];
        #pragma unroll
        for (int mf=0; mf<8; ++mf) acur[mf] = anxt[mf];
    }

    const float* cd = ch_l;
    const float* cs = ch_l + 64;
    const int h = h0 + wr;
    const size_t sparow = (size_t)(b*HH + h)*WW;
    const size_t outrow = (size_t)(b*PW + h + 1)*PW + 1;
    #pragma unroll
    for (int mf=0; mf<8; ++mf) {
        const int pixb = mf*16 + q*4;
        f32x4 sp4 = *(const f32x4*)(spa + sparow + px0 + pixb);
        float sp[4] = {sp4[0], sp4[1], sp4[2], sp4[3]};
        #pragma unroll
        for (int nf2=0; nf2<2; ++nf2) {
            int co = wn*32 + nf2*16 + lrow;
            float vcd = cd[co], vcs = cs[co];
            #pragma unroll
            for (int r=0; r<4; ++r) {
                float v;
                if (MODE==0) v = acc[mf][nf2][r] * (vcs*sp[r] + vcd);
                else         v = acc[mf][nf2][r] * (vcs*sp[r] + vcd) + acc[mf][nf2+2][r] * sp[r];
                v = fmaxf(v, 0.f);
                out[(outrow + px0 + pixb + r)*64 + co] = (f16)v;
            }
        }
    }
}

// --------------------------------------------------- collect (single pass)
// out[p,co] = sum_l fea_l[p,:] @ Wc_l + bias.  K = 256. Padded f16 inputs.
// mfma(W, X, C) -> transposed C -> f32x4 (16B) plain stores.
__global__ __launch_bounds__(256) void k_collect_all(
        const f16* __restrict__ f0, const f16* __restrict__ f1,
        const f16* __restrict__ f2, const f16* __restrict__ f3,
        const f16* __restrict__ wcpk, const float* __restrict__ bias,
        float* __restrict__ out) {
    const int wt = blockIdx.x, h = blockIdx.y, b = blockIdx.z;
    const int tid = threadIdx.x;
    const int lane = tid & 63, wid = tid >> 6;
    const int lrow = lane & 15, lk = (lane>>4)*8;
    const size_t inrow  = (size_t)(b*PW + h + 1)*PW + 1;
    const size_t outrow = (size_t)(b*HH + h)*WW;
    const int px0 = wt*256 + wid*64;

    const f16* feas[4] = {f0, f1, f2, f3};

    f32x4 acc[4][4];
    #pragma unroll
    for (int i=0;i<4;i++)
        #pragma unroll
        for (int j=0;j<4;j++) { f32x4 z = {0.f,0.f,0.f,0.f}; acc[i][j] = z; }

    #pragma unroll
    for (int kb=0; kb<8; ++kb) {
        const f16* fl = feas[kb>>1];
        f16x8 a[4];
        #pragma unroll
        for (int mf=0; mf<4; ++mf)
            a[mf] = *reinterpret_cast<const f16x8*>(fl + (inrow + px0 + mf*16 + lrow)*64 + (kb&1)*32 + lk);
        #pragma unroll
        for (int nf=0; nf<4; ++nf) {
            f16x8 bb = *reinterpret_cast<const f16x8*>(wcpk + ((size_t)(kb*4 + nf)*64 + lane)*8);
            #pragma unroll
            for (int mf=0; mf<4; ++mf)
                acc[mf][nf] = __builtin_amdgcn_mfma_f32_16x16x32_f16(bb, a[mf], acc[mf][nf], 0,0,0);
        }
    }
    const int q = lane >> 4;
    #pragma unroll
    for (int mf=0; mf<4; ++mf) {
        const int pix = px0 + mf*16 + lrow;
        float* orow = out + (outrow + pix)*CC;
        #pragma unroll
        for (int nf=0; nf<4; ++nf) {
            const int co0 = nf*16 + q*4;
            f32x4 b4 = *(const f32x4*)(bias + co0);
            *(f32x4*)(orow + co0) = acc[mf][nf] + b4;
        }
    }
}

// --------------------------------------- collect fallback (per-layer RMW)
template<bool FIRST>
__global__ __launch_bounds__(256) void k_collect(const f16* __restrict__ fea,
        const f16* __restrict__ wcpk_l, const float* __restrict__ bias,
        float* __restrict__ out) {
    const int wt = blockIdx.x, h = blockIdx.y, b = blockIdx.z;
    const int tid = threadIdx.x;
    const int lane = tid & 63, wid = tid >> 6;
    const int lrow = lane & 15, lk = (lane>>4)*8;
    const size_t inrow  = (size_t)(b*PW + h + 1)*PW + 1;
    const size_t outrow = (size_t)(b*HH + h)*WW;
    const int px0 = wt*64 + wid*16;

    f32x4 acc[4];
    #pragma unroll
    for (int j=0;j<4;j++) { f32x4 z = {0.f,0.f,0.f,0.f}; acc[j] = z; }

    #pragma unroll
    for (int kb=0; kb<2; ++kb) {
        f16x8 a = *reinterpret_cast<const f16x8*>(fea + (inrow + px0 + lrow)*64 + kb*32 + lk);
        #pragma unroll
        for (int nf=0; nf<4; ++nf) {
            f16x8 bb = *reinterpret_cast<const f16x8*>(wcpk_l + ((size_t)(kb*4 + nf)*64 + lane)*8);
            acc[nf] = __builtin_amdgcn_mfma_f32_16x16x32_f16(bb, a, acc[nf], 0,0,0);
        }
    }
    const int q = lane >> 4;
    const int pix = px0 + lrow;
    float* orow = out + (outrow + pix)*CC;
    #pragma unroll
    for (int nf=0; nf<4; ++nf) {
        const int co0 = nf*16 + q*4;
        f32x4 v = acc[nf];
        #pragma unroll
        for (int r=0;r<4;++r) {
            float x = v[r];
            if (FIRST) x += bias[co0+r];
            else       x += orow[co0+r];
            orow[co0+r] = x;
        }
    }
}

// ------------------------------------------------------------------ launch
extern "C" void kernel_launch(void* const* d_in, const int* in_sizes, int n_in,
                              void* d_out, int out_size, void* d_ws, size_t ws_size,
                              hipStream_t stream) {
    const float* x0  = (const float*)d_in[0];
    const float* spa = (const float*)d_in[1];
    const float* gum = (const float*)d_in[2];
    const float* chm = (const float*)d_in[3];
    const float* w0  = (const float*)d_in[4];
    const float* w1  = (const float*)d_in[5];
    const float* w2  = (const float*)d_in[6];
    const float* w3  = (const float*)d_in[7];
    const float* wc  = (const float*)d_in[8];
    const float* bias= (const float*)d_in[9];
    float* out = (float*)d_out;

    char* ws = (char*)d_ws;
    const size_t WBASE = (1u<<20);
    const size_t FB = 67699712ull;                 // padded fea buffer + 64KB tail
    const size_t NEED_A = WBASE + 4*FB;
    const size_t NEED_B = WBASE + 2*FB;
    if (ws_size < NEED_B) return;

    float* ws_ch = (float*)ws;
    f16* bpk0 = (f16*)(ws + 4096);
    f16* bpkL = (f16*)(ws + 4096 + 73728);
    f16* wcpk = (f16*)(ws + 4096 + 73728 + 442368);

    k_prep_ch<<<1, 256, 0, stream>>>(gum, chm, ws_ch, out + 33554432);
    k_pack<<<1072, 256, 0, stream>>>(w0, w1, w2, w3, wc, ws_ch, bpk0, bpkL, wcpk);

    dim3 gcv(2048, 1, 1);   // conv: flat grid, XCD-swizzled decode in-kernel
    dim3 gca(2, 512, 2);    // collect_all: 256-px tiles
    dim3 gcf(8, 512, 2);    // fallback collect: 64-px tiles
    dim3 ggd(129, 3, 1);    // guard: 3 buffers in one launch

    if (ws_size >= NEED_A) {
        f16* R0 = (f16*)(ws + WBASE);              // fea4 (conv3 output)
        f16* R1 = (f16*)(ws + WBASE + FB);
        f16* R2 = (f16*)(ws + WBASE + 2*FB);
        f16* R3 = (f16*)(ws + WBASE + 3*FB);
        k_guard<<<ggd, 256, 0, stream>>>(R1, R2, R3);
        k_conv<0><<<gcv, 256, 0, stream>>>(x0, R1, bpk0,          ws_ch + 0,   spa);
        k_conv<1><<<gcv, 256, 0, stream>>>(R1, R2, bpkL + 0,      ws_ch + 128, spa);
        k_conv<1><<<gcv, 256, 0, stream>>>(R2, R3, bpkL + 73728,  ws_ch + 256, spa);
        k_conv<1><<<gcv, 256, 0, stream>>>(R3, R0, bpkL + 147456, ws_ch + 384, spa);
        k_collect_all<<<gca, 256, 0, stream>>>(R1, R2, R3, R0, wcpk, bias, out);
    } else {
        f16* P0 = (f16*)(ws + WBASE);
        f16* P1 = (f16*)(ws + WBASE + FB);
        k_guard<<<ggd, 256, 0, stream>>>(P0, P1, P0);
        k_conv<0><<<gcv, 256, 0, stream>>>(x0, P1, bpk0,          ws_ch + 0,   spa);
        k_collect<true ><<<gcf, 256, 0, stream>>>(P1, wcpk + 0,     bias, out);
        k_conv<1><<<gcv, 256, 0, stream>>>(P1, P0, bpkL + 0,      ws_ch + 128, spa);
        k_collect<false><<<gcf, 256, 0, stream>>>(P0, wcpk + 4096,  bias, out);
        k_conv<1><<<gcv, 256, 0, stream>>>(P0, P1, bpkL + 73728,  ws_ch + 256, spa);
        k_collect<false><<<gcf, 256, 0, stream>>>(P1, wcpk + 8192,  bias, out);
        k_conv<1><<<gcv, 256, 0, stream>>>(P1, P0, bpkL + 147456, ws_ch + 384, spa);
        k_collect<false><<<gcf, 256, 0, stream>>>(P0, wcpk + 12288, bias, out);
    }
}